// Round 3
// baseline (520.942 us; speedup 1.0000x reference)
//
#include <hip/hip_runtime.h>
#include <stdint.h>

#define NN 16384
#define FD 128

typedef float f32x4 __attribute__((ext_vector_type(4)));
typedef float f32x16 __attribute__((ext_vector_type(16)));
typedef __bf16 bf16x8 __attribute__((ext_vector_type(8)));
typedef unsigned short u16x8 __attribute__((ext_vector_type(8)));
typedef unsigned short u16x4 __attribute__((ext_vector_type(4)));

static __device__ __forceinline__ unsigned short f2bf(float x) {
  return __builtin_bit_cast(unsigned short, (__bf16)x);
}

static __device__ __forceinline__ u16x8 pack8(f32x4 a, f32x4 b) {
  u16x8 r;
  r[0] = f2bf(a.x); r[1] = f2bf(a.y); r[2] = f2bf(a.z); r[3] = f2bf(a.w);
  r[4] = f2bf(b.x); r[5] = f2bf(b.y); r[6] = f2bf(b.z); r[7] = f2bf(b.w);
  return r;
}

// ---------------- kernel 1: norm[i] = (sum_j A[i][j])^-1/2 ----------------
// 512 blocks x 512 thr; 32 rows/block; 16 lanes per row stream it contiguously.
// Plain (non-nt) f32x4 loads, 256 per thread, unroll 8 -> deep HBM pipeline.
__global__ __launch_bounds__(512) void k_rownorm(const float* __restrict__ A,
                                                 float* __restrict__ norm) {
  const int tid = threadIdx.x;
  const int row = blockIdx.x * 32 + (tid >> 4);
  const float* ar = A + (size_t)row * NN + (size_t)(tid & 15) * 4;
  float sx = 0.f, sy = 0.f, sz = 0.f, sw = 0.f;
#pragma unroll 8
  for (int i = 0; i < 256; ++i) {
    f32x4 v = *(const f32x4*)(ar + (size_t)i * 64);
    sx += v.x; sy += v.y; sz += v.z; sw += v.w;
  }
  float s = (sx + sy) + (sz + sw);
#pragma unroll
  for (int off = 8; off > 0; off >>= 1) s += __shfl_xor(s, off, 64);
  if ((tid & 15) == 0) norm[row] = s > 0.f ? 1.f / sqrtf(s) : 0.f;
}

// ------- kernel 2: Bfrag = fragment-major bf16( norm[j] * (F @ W^T)[j][o] ) -------
// Bfrag layout: entry (t = j>>4, c = o>>5, lane l, e) at byte ((t*4+c)*64 + l)*16 + e*2
// holds norm[j]*H[j][o] with o = c*32 + (l&31), j = t*16 + (l>>5)*8 + e.
// This is exactly the mfma_32x32x16 B-operand fragment for k-tile t, col-group c.
__global__ __launch_bounds__(256) void k_fwt(const float* __restrict__ F,
                                             const float* __restrict__ W,
                                             const float* __restrict__ norm,
                                             unsigned short* __restrict__ Bfrag) {
  const int tid = threadIdx.x;
  const int wv = tid >> 6;
  const int l = tid & 63;
  const int lr = l & 31, lg = l >> 5;
  const int j0 = blockIdx.x * 32;

  const float* fp = F + (size_t)(j0 + lr) * FD + lg * 8;
  const float* wp = W + (size_t)(wv * 32 + lr) * FD + lg * 8;

  f32x16 acc;
#pragma unroll
  for (int i = 0; i < 16; ++i) acc[i] = 0.f;

#pragma unroll
  for (int kf = 0; kf < 8; ++kf) {
    f32x4 fa = *(const f32x4*)(fp + kf * 16);
    f32x4 fb = *(const f32x4*)(fp + kf * 16 + 4);
    f32x4 wa = *(const f32x4*)(wp + kf * 16);
    f32x4 wb = *(const f32x4*)(wp + kf * 16 + 4);
    bf16x8 av = __builtin_bit_cast(bf16x8, pack8(fa, fb));
    bf16x8 bv = __builtin_bit_cast(bf16x8, pack8(wa, wb));
    acc = __builtin_amdgcn_mfma_f32_32x32x16_bf16(av, bv, acc, 0, 0, 0);
  }

  // D: col(o-local) = lr, row(j-local) = (reg&3) + 8*(reg>>2) + 4*lg
  const int jt = blockIdx.x * 2;  // j0 >> 4
#pragma unroll
  for (int g = 0; g < 4; ++g) {
    const int jb = j0 + g * 8 + lg * 4;
    u16x4 q;
#pragma unroll
    for (int r2 = 0; r2 < 4; ++r2) q[r2] = f2bf(acc[g * 4 + r2] * norm[jb + r2]);
    const size_t byteoff =
        ((size_t)((jt + (g >> 1)) * 4 + wv) * 64 + (g & 1) * 32 + lr) * 16 +
        lg * 8;
    *(u16x4*)((char*)Bfrag + byteoff) = q;
  }
}

// ---------- kernel 3: out[i][o] = norm[i] * sum_j A[i][j]*(norm[j]*H[j][o]) + b[o] ----------
// BM=32, BK=256. 512 blocks x 512 thr (8 waves = 4 col-groups x 2 k-groups).
// A: global f32 (nontemporal, protects Bfrag L2 residency) -> regs -> bf16 ->
//    swizzled LDS (2 x 16 KB dbuf).
// B: fragment-major bf16 from L2, coalesced 1KB/wave global_load_dwordx4 -> regs. No B LDS.
// K-split (kg=0/1) reduced through LDS in epilogue; coalesced f32x4 out stores.
__global__ __launch_bounds__(512, 4) void k_gcn_gemm(
    const float* __restrict__ A, const unsigned short* __restrict__ Bfrag,
    const float* __restrict__ norm, const float* __restrict__ bias,
    float* __restrict__ out) {
  __shared__ __align__(16) unsigned short Alds[2][32 * 256];  // 2 x 16 KB

  const int tid = threadIdx.x;
  const int i0 = blockIdx.x * 32;

  // A staging: thread -> (row = tid>>4, 16 k-elements at (tid&15)*16)
  const int arow = tid >> 4;
  const int akseg = (tid & 15) << 4;
  const float* aptr = A + (size_t)(i0 + arow) * NN + akseg;
  const unsigned abyte =
      (unsigned)(arow * 512 + akseg * 2) ^ (unsigned)((arow & 7) << 4);

  // fragment addressing
  const int wv = tid >> 6;
  const int c = wv & 3, kg = wv >> 2;
  const int l = tid & 63;
  const int lr = l & 31, lg = l >> 5;
  const unsigned swz = (unsigned)((lr & 7) << 4);
  const unsigned arb = (unsigned)(lr * 512);
  const unsigned kgb = (unsigned)(kg * 256);  // kg*128 elements in bytes

  // B: lane base byte = ((c*64) + l)*16; per k-tile t add t*4*64*16 = t*4096
  const char* bptr = (const char*)Bfrag + (size_t)(c * 64 + l) * 16 +
                     (size_t)kg * 8 * 4096;

  f32x16 acc;
#pragma unroll
  for (int i = 0; i < 16; ++i) acc[i] = 0.f;

  // prologue: stage tile 0 into buffer 0
  {
    f32x4 r0 = __builtin_nontemporal_load((const f32x4*)(aptr));
    f32x4 r1 = __builtin_nontemporal_load((const f32x4*)(aptr + 4));
    f32x4 r2 = __builtin_nontemporal_load((const f32x4*)(aptr + 8));
    f32x4 r3 = __builtin_nontemporal_load((const f32x4*)(aptr + 12));
    *(u16x8*)((char*)Alds[0] + abyte) = pack8(r0, r1);
    *(u16x8*)((char*)Alds[0] + (abyte ^ 16u)) = pack8(r2, r3);
  }
  __syncthreads();

#define GSTEP(CUR, NXT, S)                                                  \
  {                                                                         \
    const int s_ = (S);                                                     \
    const bool pf_ = (s_ + 1) < 64;                                         \
    f32x4 r0 = {}, r1 = {}, r2 = {}, r3 = {};                               \
    if (pf_) {                                                              \
      const float* ap_ = aptr + (size_t)(s_ + 1) * 256;                     \
      r0 = __builtin_nontemporal_load((const f32x4*)(ap_));                 \
      r1 = __builtin_nontemporal_load((const f32x4*)(ap_ + 4));             \
      r2 = __builtin_nontemporal_load((const f32x4*)(ap_ + 8));             \
      r3 = __builtin_nontemporal_load((const f32x4*)(ap_ + 12));            \
    }                                                                       \
    const char* bp_ = bptr + (size_t)s_ * (16 * 4096);                      \
    _Pragma("unroll") for (int kf = 0; kf < 8; ++kf) {                      \
      u16x8 bv = *(const u16x8*)(bp_ + (size_t)kf * 4096);                  \
      unsigned ko = (kgb + (unsigned)(kf * 32) + (unsigned)(lg * 16)) ^ swz;\
      u16x8 av = *(const u16x8*)((const char*)Alds[CUR] + (arb + ko));      \
      acc = __builtin_amdgcn_mfma_f32_32x32x16_bf16(                        \
          __builtin_bit_cast(bf16x8, av), __builtin_bit_cast(bf16x8, bv),   \
          acc, 0, 0, 0);                                                    \
    }                                                                       \
    if (pf_) {                                                              \
      *(u16x8*)((char*)Alds[NXT] + abyte) = pack8(r0, r1);                  \
      *(u16x8*)((char*)Alds[NXT] + (abyte ^ 16u)) = pack8(r2, r3);          \
    }                                                                       \
    __syncthreads();                                                        \
  }

#pragma unroll 1
  for (int s = 0; s < 64; s += 2) {
    GSTEP(0, 1, s)
    GSTEP(1, 0, s + 1)
  }
#undef GSTEP

  // ---- epilogue: reduce kg halves via LDS, then coalesced store ----
  // D: col(o-local) = c*32 + lr, row(i-local) = g*8 + lg*4 + r2
  float* red = (float*)Alds;  // 32x128 f32 = 16 KB (loop's final barrier passed)
  if (kg == 1) {
#pragma unroll
    for (int g = 0; g < 4; ++g) {
      const int jb = g * 8 + lg * 4;
#pragma unroll
      for (int r2 = 0; r2 < 4; ++r2)
        red[(jb + r2) * 128 + c * 32 + lr] = acc[g * 4 + r2];
    }
  }
  __syncthreads();
  if (kg == 0) {
#pragma unroll
    for (int g = 0; g < 4; ++g) {
      const int jb = g * 8 + lg * 4;
#pragma unroll
      for (int r2 = 0; r2 < 4; ++r2)
        red[(jb + r2) * 128 + c * 32 + lr] += acc[g * 4 + r2];
    }
  }
  __syncthreads();

  {
    const int row = tid >> 4;            // 0..31
    const int colseg = (tid & 15) * 8;   // 0..120
    const float nm = norm[i0 + row];
    f32x4 v0 = *(const f32x4*)(red + row * 128 + colseg);
    f32x4 v1 = *(const f32x4*)(red + row * 128 + colseg + 4);
    f32x4 b0 = *(const f32x4*)(bias + colseg);
    f32x4 b1 = *(const f32x4*)(bias + colseg + 4);
    f32x4 o0, o1;
    o0.x = nm * v0.x + b0.x; o0.y = nm * v0.y + b0.y;
    o0.z = nm * v0.z + b0.z; o0.w = nm * v0.w + b0.w;
    o1.x = nm * v1.x + b1.x; o1.y = nm * v1.y + b1.y;
    o1.z = nm * v1.z + b1.z; o1.w = nm * v1.w + b1.w;
    float* op = out + (size_t)(i0 + row) * FD + colseg;
    *(f32x4*)op = o0;
    *(f32x4*)(op + 4) = o1;
  }
}

extern "C" void kernel_launch(void* const* d_in, const int* in_sizes, int n_in,
                              void* d_out, int out_size, void* d_ws,
                              size_t ws_size, hipStream_t stream) {
  (void)in_sizes; (void)n_in; (void)out_size; (void)ws_size;
  const float* A = (const float*)d_in[0];
  const float* F = (const float*)d_in[1];
  const float* W = (const float*)d_in[2];
  const float* b = (const float*)d_in[3];
  float* out = (float*)d_out;

  float* norm = (float*)d_ws;                                     // 64 KB
  unsigned short* Bfrag = (unsigned short*)((char*)d_ws + 65536); // 4 MB

  k_rownorm<<<NN / 32, 512, 0, stream>>>(A, norm);
  k_fwt<<<NN / 32, 256, 0, stream>>>(F, W, norm, Bfrag);
  k_gcn_gemm<<<NN / 32, 512, 0, stream>>>(A, Bfrag, norm, b, out);
}

// Round 4
// 515.569 us; speedup vs baseline: 1.0104x; 1.0104x over previous
//
#include <hip/hip_runtime.h>
#include <stdint.h>

#define NN 16384
#define FD 128

typedef float f32x4 __attribute__((ext_vector_type(4)));
typedef float f32x16 __attribute__((ext_vector_type(16)));
typedef __bf16 bf16x8 __attribute__((ext_vector_type(8)));
typedef unsigned short u16x8 __attribute__((ext_vector_type(8)));
typedef unsigned short u16x4 __attribute__((ext_vector_type(4)));

static __device__ __forceinline__ unsigned short f2bf(float x) {
  return __builtin_bit_cast(unsigned short, (__bf16)x);
}

static __device__ __forceinline__ u16x8 pack8(f32x4 a, f32x4 b) {
  u16x8 r;
  r[0] = f2bf(a.x); r[1] = f2bf(a.y); r[2] = f2bf(a.z); r[3] = f2bf(a.w);
  r[4] = f2bf(b.x); r[5] = f2bf(b.y); r[6] = f2bf(b.z); r[7] = f2bf(b.w);
  return r;
}

// ---------------- kernel 1: norm[i] = (sum_j A[i][j])^-1/2 ----------------
// (R1/R2 version — R3 variant was neutral; reverted for clean attribution)
__global__ __launch_bounds__(256) void k_rownorm(const float* __restrict__ A,
                                                 float* __restrict__ norm) {
  const int row = blockIdx.x;
  const f32x4* ar = (const f32x4*)(A + (size_t)row * NN);
  float s = 0.f;
#pragma unroll 4
  for (int c = threadIdx.x; c < NN / 4; c += 256) {
    f32x4 v = __builtin_nontemporal_load(&ar[c]);
    s += (v.x + v.y) + (v.z + v.w);
  }
#pragma unroll
  for (int off = 32; off > 0; off >>= 1) s += __shfl_xor(s, off, 64);
  __shared__ float red[4];
  const int lane = threadIdx.x & 63, w = threadIdx.x >> 6;
  if (lane == 0) red[w] = s;
  __syncthreads();
  if (threadIdx.x == 0) {
    float d = (red[0] + red[1]) + (red[2] + red[3]);
    norm[row] = d > 0.f ? 1.f / sqrtf(d) : 0.f;
  }
}

// ------- kernel 2: Bfrag = fragment-major bf16( norm[j] * (F @ W^T)[j][o] ) -------
// Bfrag layout: entry (t = j>>4, c = o>>5, lane l, e) at byte ((t*4+c)*64 + l)*16 + e*2
// holds norm[j]*H[j][o] with o = c*32 + (l&31), j = t*16 + (l>>5)*8 + e.
__global__ __launch_bounds__(256) void k_fwt(const float* __restrict__ F,
                                             const float* __restrict__ W,
                                             const float* __restrict__ norm,
                                             unsigned short* __restrict__ Bfrag) {
  const int tid = threadIdx.x;
  const int wv = tid >> 6;
  const int l = tid & 63;
  const int lr = l & 31, lg = l >> 5;
  const int j0 = blockIdx.x * 32;

  const float* fp = F + (size_t)(j0 + lr) * FD + lg * 8;
  const float* wp = W + (size_t)(wv * 32 + lr) * FD + lg * 8;

  f32x16 acc;
#pragma unroll
  for (int i = 0; i < 16; ++i) acc[i] = 0.f;

#pragma unroll
  for (int kf = 0; kf < 8; ++kf) {
    f32x4 fa = *(const f32x4*)(fp + kf * 16);
    f32x4 fb = *(const f32x4*)(fp + kf * 16 + 4);
    f32x4 wa = *(const f32x4*)(wp + kf * 16);
    f32x4 wb = *(const f32x4*)(wp + kf * 16 + 4);
    bf16x8 av = __builtin_bit_cast(bf16x8, pack8(fa, fb));
    bf16x8 bv = __builtin_bit_cast(bf16x8, pack8(wa, wb));
    acc = __builtin_amdgcn_mfma_f32_32x32x16_bf16(av, bv, acc, 0, 0, 0);
  }

  const int jt = blockIdx.x * 2;  // j0 >> 4
#pragma unroll
  for (int g = 0; g < 4; ++g) {
    const int jb = j0 + g * 8 + lg * 4;
    u16x4 q;
#pragma unroll
    for (int r2 = 0; r2 < 4; ++r2) q[r2] = f2bf(acc[g * 4 + r2] * norm[jb + r2]);
    const size_t byteoff =
        ((size_t)((jt + (g >> 1)) * 4 + wv) * 64 + (g & 1) * 32 + lr) * 16 +
        lg * 8;
    *(u16x4*)((char*)Bfrag + byteoff) = q;
  }
}

// ---------- kernel 3: out[i][o] = norm[i] * sum_j A[i][j]*(norm[j]*H[j][o]) + b[o] ----------
// BM=64, BK=256. 256 blocks x 1024 thr (16 waves = 4 col x 2 m-sub x 2 k-groups).
// Halves per-chip B traffic vs BM=32 (each block reads the full 4MB Bfrag once:
// 256 x 4MB = 1 GB instead of 2 GB over the LLC->L2 path).
// A: global f32 (nontemporal) -> regs -> bf16 -> swizzled LDS (2 x 32 KB dbuf).
// B: fragment-major bf16 from L2/LLC, coalesced 1KB/wave dwordx4 -> regs; m-subtile
//    pairs reuse the same B fragment. K-split (kg) reduced via LDS in epilogue.
__global__ __launch_bounds__(1024, 4) void k_gcn_gemm(
    const float* __restrict__ A, const unsigned short* __restrict__ Bfrag,
    const float* __restrict__ norm, const float* __restrict__ bias,
    float* __restrict__ out) {
  __shared__ __align__(16) unsigned short Alds[2][64 * 256];  // 2 x 32 KB

  const int tid = threadIdx.x;
  const int i0 = blockIdx.x * 64;

  // A staging: thread -> (row = tid>>4, 16 f32 k-elements at (tid&15)*16)
  const int arow = tid >> 4;
  const int akseg = (tid & 15) << 4;
  const float* aptr = A + (size_t)(i0 + arow) * NN + akseg;
  const unsigned abyte =
      (unsigned)(arow * 512 + akseg * 2) ^ (unsigned)((arow & 15) << 4);

  // fragment addressing
  const int wv = tid >> 6;          // 0..15
  const int c = wv & 3;             // col-group: o in [c*32, c*32+32)
  const int m = (wv >> 2) & 1;      // m-subtile: rows m*32..m*32+31
  const int kg = wv >> 3;           // k-half within BK=256
  const int l = tid & 63;
  const int lr = l & 31, lg = l >> 5;
  const int rowl = m * 32 + lr;
  const unsigned swz = (unsigned)((rowl & 15) << 4);
  const unsigned arb = (unsigned)(rowl * 512);
  const unsigned kgb = (unsigned)(kg * 256);  // kg*128 elements, bytes

  // B: lane base byte = (c*64 + l)*16; k-tile t adds t*4096; kg offsets 8 tiles
  const char* bptr = (const char*)Bfrag + (size_t)(c * 64 + l) * 16 +
                     (size_t)kg * 8 * 4096;

  f32x16 acc;
#pragma unroll
  for (int i = 0; i < 16; ++i) acc[i] = 0.f;

  // prologue: stage tile 0 into buffer 0
  {
    f32x4 r0 = __builtin_nontemporal_load((const f32x4*)(aptr));
    f32x4 r1 = __builtin_nontemporal_load((const f32x4*)(aptr + 4));
    f32x4 r2 = __builtin_nontemporal_load((const f32x4*)(aptr + 8));
    f32x4 r3 = __builtin_nontemporal_load((const f32x4*)(aptr + 12));
    *(u16x8*)((char*)Alds[0] + abyte) = pack8(r0, r1);
    *(u16x8*)((char*)Alds[0] + (abyte ^ 16u)) = pack8(r2, r3);
  }
  __syncthreads();

#define GSTEP(CUR, NXT, S)                                                  \
  {                                                                         \
    const int s_ = (S);                                                     \
    const bool pf_ = (s_ + 1) < 64;                                         \
    f32x4 r0 = {}, r1 = {}, r2 = {}, r3 = {};                               \
    if (pf_) {                                                              \
      const float* ap_ = aptr + (size_t)(s_ + 1) * 256;                     \
      r0 = __builtin_nontemporal_load((const f32x4*)(ap_));                 \
      r1 = __builtin_nontemporal_load((const f32x4*)(ap_ + 4));             \
      r2 = __builtin_nontemporal_load((const f32x4*)(ap_ + 8));             \
      r3 = __builtin_nontemporal_load((const f32x4*)(ap_ + 12));            \
    }                                                                       \
    const char* bp_ = bptr + (size_t)s_ * (16 * 4096);                      \
    _Pragma("unroll") for (int kf = 0; kf < 8; ++kf) {                      \
      u16x8 bv = *(const u16x8*)(bp_ + (size_t)kf * 4096);                  \
      unsigned ko = (kgb + (unsigned)(kf * 32) + (unsigned)(lg * 16)) ^ swz;\
      u16x8 av = *(const u16x8*)((const char*)Alds[CUR] + (arb + ko));      \
      acc = __builtin_amdgcn_mfma_f32_32x32x16_bf16(                        \
          __builtin_bit_cast(bf16x8, av), __builtin_bit_cast(bf16x8, bv),   \
          acc, 0, 0, 0);                                                    \
    }                                                                       \
    if (pf_) {                                                              \
      *(u16x8*)((char*)Alds[NXT] + abyte) = pack8(r0, r1);                  \
      *(u16x8*)((char*)Alds[NXT] + (abyte ^ 16u)) = pack8(r2, r3);          \
    }                                                                       \
    __syncthreads();                                                        \
  }

#pragma unroll 1
  for (int s = 0; s < 64; s += 2) {
    GSTEP(0, 1, s)
    GSTEP(1, 0, s + 1)
  }
#undef GSTEP

  // ---- epilogue: reduce kg halves via LDS, then coalesced store ----
  // D: col(o-local) = c*32 + lr, row(i-local) = m*32 + g*8 + lg*4 + r2
  float* red = (float*)Alds;  // 64x128 f32 = 32 KB (final loop barrier passed)
  if (kg == 1) {
#pragma unroll
    for (int g = 0; g < 4; ++g) {
      const int jb = m * 32 + g * 8 + lg * 4;
#pragma unroll
      for (int r2 = 0; r2 < 4; ++r2)
        red[(jb + r2) * 128 + c * 32 + lr] = acc[g * 4 + r2];
    }
  }
  __syncthreads();
  if (kg == 0) {
#pragma unroll
    for (int g = 0; g < 4; ++g) {
      const int jb = m * 32 + g * 8 + lg * 4;
#pragma unroll
      for (int r2 = 0; r2 < 4; ++r2)
        red[(jb + r2) * 128 + c * 32 + lr] += acc[g * 4 + r2];
    }
  }
  __syncthreads();

  {
    const int row = tid >> 4;            // 0..63
    const int colseg = (tid & 15) * 8;   // 0..120
    const float nm = norm[i0 + row];
    f32x4 v0 = *(const f32x4*)(red + row * 128 + colseg);
    f32x4 v1 = *(const f32x4*)(red + row * 128 + colseg + 4);
    f32x4 b0 = *(const f32x4*)(bias + colseg);
    f32x4 b1 = *(const f32x4*)(bias + colseg + 4);
    f32x4 o0, o1;
    o0.x = nm * v0.x + b0.x; o0.y = nm * v0.y + b0.y;
    o0.z = nm * v0.z + b0.z; o0.w = nm * v0.w + b0.w;
    o1.x = nm * v1.x + b1.x; o1.y = nm * v1.y + b1.y;
    o1.z = nm * v1.z + b1.z; o1.w = nm * v1.w + b1.w;
    float* op = out + (size_t)(i0 + row) * FD + colseg;
    *(f32x4*)op = o0;
    *(f32x4*)(op + 4) = o1;
  }
}

extern "C" void kernel_launch(void* const* d_in, const int* in_sizes, int n_in,
                              void* d_out, int out_size, void* d_ws,
                              size_t ws_size, hipStream_t stream) {
  (void)in_sizes; (void)n_in; (void)out_size; (void)ws_size;
  const float* A = (const float*)d_in[0];
  const float* F = (const float*)d_in[1];
  const float* W = (const float*)d_in[2];
  const float* b = (const float*)d_in[3];
  float* out = (float*)d_out;

  float* norm = (float*)d_ws;                                     // 64 KB
  unsigned short* Bfrag = (unsigned short*)((char*)d_ws + 65536); // 4 MB

  k_rownorm<<<NN, 256, 0, stream>>>(A, norm);
  k_fwt<<<NN / 32, 256, 0, stream>>>(F, W, norm, Bfrag);
  k_gcn_gemm<<<NN / 64, 1024, 0, stream>>>(A, Bfrag, norm, b, out);
}

// Round 5
// 393.411 us; speedup vs baseline: 1.3242x; 1.3105x over previous
//
#include <hip/hip_runtime.h>
#include <stdint.h>

#define NN 16384
#define FD 128

typedef float f32x4 __attribute__((ext_vector_type(4)));
typedef float f32x16 __attribute__((ext_vector_type(16)));
typedef __bf16 bf16x8 __attribute__((ext_vector_type(8)));
typedef unsigned short u16x8 __attribute__((ext_vector_type(8)));
typedef unsigned short u16x4 __attribute__((ext_vector_type(4)));

static __device__ __forceinline__ unsigned short f2bf(float x) {
  return __builtin_bit_cast(unsigned short, (__bf16)x);
}

static __device__ __forceinline__ u16x8 pack8(f32x4 a, f32x4 b) {
  u16x8 r;
  r[0] = f2bf(a.x); r[1] = f2bf(a.y); r[2] = f2bf(a.z); r[3] = f2bf(a.w);
  r[4] = f2bf(b.x); r[5] = f2bf(b.y); r[6] = f2bf(b.z); r[7] = f2bf(b.w);
  return r;
}

static __device__ __forceinline__ u16x4 pack4(f32x4 a) {
  u16x4 r;
  r[0] = f2bf(a.x); r[1] = f2bf(a.y); r[2] = f2bf(a.z); r[3] = f2bf(a.w);
  return r;
}

// ---------------- kernel 1: norm[i] = (sum_j A[i][j])^-1/2 ----------------
__global__ __launch_bounds__(256) void k_rownorm(const float* __restrict__ A,
                                                 float* __restrict__ norm) {
  const int row = blockIdx.x;
  const f32x4* ar = (const f32x4*)(A + (size_t)row * NN);
  float s = 0.f;
#pragma unroll 4
  for (int c = threadIdx.x; c < NN / 4; c += 256) {
    f32x4 v = __builtin_nontemporal_load(&ar[c]);
    s += (v.x + v.y) + (v.z + v.w);
  }
#pragma unroll
  for (int off = 32; off > 0; off >>= 1) s += __shfl_xor(s, off, 64);
  __shared__ float red[4];
  const int lane = threadIdx.x & 63, w = threadIdx.x >> 6;
  if (lane == 0) red[w] = s;
  __syncthreads();
  if (threadIdx.x == 0) {
    float d = (red[0] + red[1]) + (red[2] + red[3]);
    norm[row] = d > 0.f ? 1.f / sqrtf(d) : 0.f;
  }
}

// ------- kernel 2: Bfrag = fragment-major bf16( norm[j] * (F @ W^T)[j][o] ) -------
// Bfrag layout: entry (t = j>>4, c = o>>5, lane l, e) at byte ((t*4+c)*64 + l)*16 + e*2
// holds norm[j]*H[j][o] with o = c*32 + (l&31), j = t*16 + (l>>5)*8 + e.
__global__ __launch_bounds__(256) void k_fwt(const float* __restrict__ F,
                                             const float* __restrict__ W,
                                             const float* __restrict__ norm,
                                             unsigned short* __restrict__ Bfrag) {
  const int tid = threadIdx.x;
  const int wv = tid >> 6;
  const int l = tid & 63;
  const int lr = l & 31, lg = l >> 5;
  const int j0 = blockIdx.x * 32;

  const float* fp = F + (size_t)(j0 + lr) * FD + lg * 8;
  const float* wp = W + (size_t)(wv * 32 + lr) * FD + lg * 8;

  f32x16 acc;
#pragma unroll
  for (int i = 0; i < 16; ++i) acc[i] = 0.f;

#pragma unroll
  for (int kf = 0; kf < 8; ++kf) {
    f32x4 fa = *(const f32x4*)(fp + kf * 16);
    f32x4 fb = *(const f32x4*)(fp + kf * 16 + 4);
    f32x4 wa = *(const f32x4*)(wp + kf * 16);
    f32x4 wb = *(const f32x4*)(wp + kf * 16 + 4);
    bf16x8 av = __builtin_bit_cast(bf16x8, pack8(fa, fb));
    bf16x8 bv = __builtin_bit_cast(bf16x8, pack8(wa, wb));
    acc = __builtin_amdgcn_mfma_f32_32x32x16_bf16(av, bv, acc, 0, 0, 0);
  }

  const int jt = blockIdx.x * 2;  // j0 >> 4
#pragma unroll
  for (int g = 0; g < 4; ++g) {
    const int jb = j0 + g * 8 + lg * 4;
    u16x4 q;
#pragma unroll
    for (int r2 = 0; r2 < 4; ++r2) q[r2] = f2bf(acc[g * 4 + r2] * norm[jb + r2]);
    const size_t byteoff =
        ((size_t)((jt + (g >> 1)) * 4 + wv) * 64 + (g & 1) * 32 + lr) * 16 +
        lg * 8;
    *(u16x4*)((char*)Bfrag + byteoff) = q;
  }
}

// ---------- kernel 3: out[i][o] = norm[i] * sum_j A[i][j]*(norm[j]*H[j][o]) + b[o] ----------
// BM=64, BK=256. 256 blocks x 1024 thr (16 waves = 4 col x 2 m-sub x 2 k-groups).
// A staging v2: per-INSTRUCTION wave-contiguous loads. Load i (0..3): wave w reads
// row i*16+w, lane l reads f32x4 at col l*4 -> 64 lanes x 16 B = 1 KB contiguous,
// every 64-B line fetched exactly once by exactly one instruction (nt now harmless).
// LDS: pack f32x4 -> u16x4, ds_write_b64 at byte (row*512 + l*8) ^ ((row&15)<<4).
// B: fragment-major bf16 from L2/LLC, coalesced 1KB/wave dwordx4 -> regs.
// K-split (kg) reduced via LDS in epilogue; coalesced f32x4 out stores.
__global__ __launch_bounds__(1024, 4) void k_gcn_gemm(
    const float* __restrict__ A, const unsigned short* __restrict__ Bfrag,
    const float* __restrict__ norm, const float* __restrict__ bias,
    float* __restrict__ out) {
  __shared__ __align__(16) unsigned short Alds[2][64 * 256];  // 2 x 32 KB

  const int tid = threadIdx.x;
  const int i0 = blockIdx.x * 64;

  // A staging: wave w = srow, lane sl; load i covers row i*16+srow
  const int srow = tid >> 6;   // 0..15
  const int sl = tid & 63;
  const float* aptr = A + (size_t)(i0 + srow) * NN + (size_t)sl * 4;
  // write byte for load i = i*8192 + abase  (row&15 == srow)
  const unsigned abase =
      (unsigned)(srow * 512) + ((unsigned)(sl * 8) ^ (unsigned)(srow << 4));

  // fragment addressing
  const int wv = tid >> 6;          // 0..15
  const int c = wv & 3;             // col-group: o in [c*32, c*32+32)
  const int m = (wv >> 2) & 1;      // m-subtile: rows m*32..m*32+31
  const int kg = wv >> 3;           // k-half within BK=256
  const int l = tid & 63;
  const int lr = l & 31, lg = l >> 5;
  const int rowl = m * 32 + lr;
  const unsigned swz = (unsigned)((rowl & 15) << 4);
  const unsigned arb = (unsigned)(rowl * 512);
  const unsigned kgb = (unsigned)(kg * 256);  // kg*128 elements, bytes

  // B: lane base byte = (c*64 + l)*16; k-tile t adds t*4096; kg offsets 8 tiles
  const char* bptr = (const char*)Bfrag + (size_t)(c * 64 + l) * 16 +
                     (size_t)kg * 8 * 4096;

  f32x16 acc;
#pragma unroll
  for (int i = 0; i < 16; ++i) acc[i] = 0.f;

#define ALOAD(RV, S, I)                                                     \
  RV = __builtin_nontemporal_load(                                          \
      (const f32x4*)(aptr + (size_t)(S) * 256 + (size_t)(I) * (16 * NN)));
#define AWRITE(BUF, RV, I)                                                  \
  *(u16x4*)((char*)Alds[BUF] + (abase + (I) * 8192)) = pack4(RV);

  // prologue: stage tile 0 into buffer 0
  {
    f32x4 r0, r1, r2, r3;
    ALOAD(r0, 0, 0) ALOAD(r1, 0, 1) ALOAD(r2, 0, 2) ALOAD(r3, 0, 3)
    AWRITE(0, r0, 0) AWRITE(0, r1, 1) AWRITE(0, r2, 2) AWRITE(0, r3, 3)
  }
  __syncthreads();

#define GSTEP(CUR, NXT, S)                                                  \
  {                                                                         \
    const int s_ = (S);                                                     \
    const bool pf_ = (s_ + 1) < 64;                                         \
    f32x4 r0 = {}, r1 = {}, r2 = {}, r3 = {};                               \
    if (pf_) {                                                              \
      ALOAD(r0, s_ + 1, 0) ALOAD(r1, s_ + 1, 1)                             \
      ALOAD(r2, s_ + 1, 2) ALOAD(r3, s_ + 1, 3)                             \
    }                                                                       \
    const char* bp_ = bptr + (size_t)s_ * (16 * 4096);                      \
    _Pragma("unroll") for (int kf = 0; kf < 8; ++kf) {                      \
      u16x8 bv = *(const u16x8*)(bp_ + (size_t)kf * 4096);                  \
      unsigned ko = (kgb + (unsigned)(kf * 32) + (unsigned)(lg * 16)) ^ swz;\
      u16x8 av = *(const u16x8*)((const char*)Alds[CUR] + (arb + ko));      \
      acc = __builtin_amdgcn_mfma_f32_32x32x16_bf16(                        \
          __builtin_bit_cast(bf16x8, av), __builtin_bit_cast(bf16x8, bv),   \
          acc, 0, 0, 0);                                                    \
    }                                                                       \
    if (pf_) {                                                              \
      AWRITE(NXT, r0, 0) AWRITE(NXT, r1, 1)                                 \
      AWRITE(NXT, r2, 2) AWRITE(NXT, r3, 3)                                 \
    }                                                                       \
    __syncthreads();                                                        \
  }

#pragma unroll 1
  for (int s = 0; s < 64; s += 2) {
    GSTEP(0, 1, s)
    GSTEP(1, 0, s + 1)
  }
#undef GSTEP
#undef ALOAD
#undef AWRITE

  // ---- epilogue: reduce kg halves via LDS, then coalesced store ----
  // D: col(o-local) = c*32 + lr, row(i-local) = m*32 + g*8 + lg*4 + r2
  float* red = (float*)Alds;  // 64x128 f32 = 32 KB (final loop barrier passed)
  if (kg == 1) {
#pragma unroll
    for (int g = 0; g < 4; ++g) {
      const int jb = m * 32 + g * 8 + lg * 4;
#pragma unroll
      for (int r2 = 0; r2 < 4; ++r2)
        red[(jb + r2) * 128 + c * 32 + lr] = acc[g * 4 + r2];
    }
  }
  __syncthreads();
  if (kg == 0) {
#pragma unroll
    for (int g = 0; g < 4; ++g) {
      const int jb = m * 32 + g * 8 + lg * 4;
#pragma unroll
      for (int r2 = 0; r2 < 4; ++r2)
        red[(jb + r2) * 128 + c * 32 + lr] += acc[g * 4 + r2];
    }
  }
  __syncthreads();

  {
    const int row = tid >> 4;            // 0..63
    const int colseg = (tid & 15) * 8;   // 0..120
    const float nm = norm[i0 + row];
    f32x4 v0 = *(const f32x4*)(red + row * 128 + colseg);
    f32x4 v1 = *(const f32x4*)(red + row * 128 + colseg + 4);
    f32x4 b0 = *(const f32x4*)(bias + colseg);
    f32x4 b1 = *(const f32x4*)(bias + colseg + 4);
    f32x4 o0, o1;
    o0.x = nm * v0.x + b0.x; o0.y = nm * v0.y + b0.y;
    o0.z = nm * v0.z + b0.z; o0.w = nm * v0.w + b0.w;
    o1.x = nm * v1.x + b1.x; o1.y = nm * v1.y + b1.y;
    o1.z = nm * v1.z + b1.z; o1.w = nm * v1.w + b1.w;
    float* op = out + (size_t)(i0 + row) * FD + colseg;
    *(f32x4*)op = o0;
    *(f32x4*)(op + 4) = o1;
  }
}

extern "C" void kernel_launch(void* const* d_in, const int* in_sizes, int n_in,
                              void* d_out, int out_size, void* d_ws,
                              size_t ws_size, hipStream_t stream) {
  (void)in_sizes; (void)n_in; (void)out_size; (void)ws_size;
  const float* A = (const float*)d_in[0];
  const float* F = (const float*)d_in[1];
  const float* W = (const float*)d_in[2];
  const float* b = (const float*)d_in[3];
  float* out = (float*)d_out;

  float* norm = (float*)d_ws;                                     // 64 KB
  unsigned short* Bfrag = (unsigned short*)((char*)d_ws + 65536); // 4 MB

  k_rownorm<<<NN, 256, 0, stream>>>(A, norm);
  k_fwt<<<NN / 32, 256, 0, stream>>>(F, W, norm, Bfrag);
  k_gcn_gemm<<<NN / 64, 1024, 0, stream>>>(A, Bfrag, norm, b, out);
}